// Round 4
// baseline (179.144 us; speedup 1.0000x reference)
//
#include <hip/hip_runtime.h>
#include <hip/hip_cooperative_groups.h>

namespace cg = cooperative_groups;

// DinoPool: block-diagonal uniform attention == per-512-row-block column mean,
// broadcast to all 512 rows. x, out: [4,4096,384] float32. x1/x2/mask unused.
//
// R3 passed at 143.8 us; profile shows harness re-poison fills (256 MiB d_ws
// @40us, 83% HBM peak) dominate dur_us. Controllable slice ~14us (2 kernels).
// This round: single cooperative kernel (1 launch, min HBM traffic 50.3 MB).

#define BB   4
#define SS   4096
#define CC   384          // H*D = 6*64
#define BLK  512
#define NBLK 8            // SS/BLK
#define NT   384          // threads per WG (6 waves)
#define RCH  8            // producer WGs per block
#define ROWS (BLK / RCH)  // 64 rows per WG (both phases)

// grid = BB*NBLK*RCH = 256 WGs (one per CU; 6 waves/CU -> co-resident).
__global__ __launch_bounds__(NT) void dinopool_coop(
    const float* __restrict__ x, float* __restrict__ ws,
    float* __restrict__ out) {
  int bid = blockIdx.x;               // (b*NBLK + blk)*RCH + r
  int r   = bid & (RCH - 1);
  int blk = (bid >> 3) & (NBLK - 1);
  int b   = bid >> 6;
  int t   = threadIdx.x;

  // ---- phase A: 64-row partial column sum (thread t = channel t) ----------
  const float* p = x + (size_t)(b * SS + blk * BLK + r * ROWS) * CC + t;
  float acc = 0.0f;
#pragma unroll 16
  for (int i = 0; i < ROWS; ++i) acc += p[(size_t)i * CC];
  ws[(size_t)bid * CC + t] = acc;

  cg::this_grid().sync();

  // ---- phase B: reduce 8 partials -> mean; broadcast-write own 64 rows ----
  __shared__ __align__(16) float smean[CC];
  const float* wp = ws + (size_t)((b * NBLK + blk) * RCH) * CC + t;
  float s = 0.0f;
#pragma unroll
  for (int k = 0; k < RCH; ++k) s += wp[(size_t)k * CC];
  smean[t] = s * (1.0f / (float)BLK);
  __syncthreads();

  const float4* sv = (const float4*)smean;  // 96 float4 per row
  float4* ov = (float4*)(out + (size_t)(b * SS + blk * BLK + r * ROWS) * CC);
  const int total = ROWS * (CC / 4);        // 64*96 = 6144
  for (int i = t; i < total; i += NT) ov[i] = sv[i % 96];
}

// ---- proven two-kernel fallback (R3, 143.8us) if coop launch refuses ------
__global__ __launch_bounds__(NT) void colsum_f32(
    const float* __restrict__ x, float* __restrict__ ws) {
  int bid = blockIdx.x;
  int r   = bid & (RCH - 1);
  int blk = (bid >> 3) & (NBLK - 1);
  int b   = bid >> 6;
  int c   = threadIdx.x;
  const float* p = x + (size_t)(b * SS + blk * BLK + r * ROWS) * CC + c;
  float acc = 0.0f;
#pragma unroll 16
  for (int i = 0; i < ROWS; ++i) acc += p[(size_t)i * CC];
  ws[(size_t)bid * CC + c] = acc;
}

__global__ __launch_bounds__(NT) void bcast_f32(
    const float* __restrict__ ws, float* __restrict__ out) {
  __shared__ __align__(16) float smean[CC];
  int bid = blockIdx.x;               // (b*NBLK + blk)*16 + sub
  int sub = bid & 15;
  int blk = (bid >> 4) & (NBLK - 1);
  int b   = bid >> 7;
  int t   = threadIdx.x;
  const float* wp = ws + (size_t)((b * NBLK + blk) * RCH) * CC + t;
  float s = 0.0f;
#pragma unroll
  for (int k = 0; k < RCH; ++k) s += wp[(size_t)k * CC];
  smean[t] = s * (1.0f / (float)BLK);
  __syncthreads();
  const float4* sv = (const float4*)smean;
  float4* ov = (float4*)(out + (size_t)(b * SS + blk * BLK + sub * 32) * CC);
  const int total = 32 * (CC / 4);
  for (int i = t; i < total; i += NT) ov[i] = sv[i % 96];
}

extern "C" void kernel_launch(void* const* d_in, const int* in_sizes, int n_in,
                              void* d_out, int out_size, void* d_ws,
                              size_t ws_size, hipStream_t stream) {
  const float* x = (const float*)d_in[0];
  float* out = (float*)d_out;
  float* ws = (float*)d_ws;  // needs 256*384*4 = 393 KB (ws_size = 256 MiB)

  void* args[] = {(void*)&x, (void*)&ws, (void*)&out};
  hipError_t err = hipLaunchCooperativeKernel(
      (const void*)dinopool_coop, dim3(BB * NBLK * RCH), dim3(NT), args, 0,
      stream);
  if (err != hipSuccess) {
    // fallback: proven two-kernel path
    colsum_f32<<<BB * NBLK * RCH, NT, 0, stream>>>(x, ws);
    bcast_f32<<<BB * NBLK * 16, NT, 0, stream>>>(ws, out);
  }
}

// Round 5
// 153.020 us; speedup vs baseline: 1.1707x; 1.1707x over previous
//
#include <hip/hip_runtime.h>

// DinoPool: block-diagonal uniform attention == per-512-row-block column mean,
// broadcast to all 512 rows. x, out: [4,4096,384] float32. x1/x2/mask unused.
//
// R4 post-mortem: cooperative kernel REGRESSED (143.8 -> 179.1 us) — coop
// dispatch overhead + grid-sync straggler drain. Reverted.
// R5: ONE plain kernel, 512 WGs. Each WG redundantly reduces its (b,blk)
// block (16x read amplification served by per-XCD L2 via bid swizzle:
// bid = sub*32 + group keeps all 16 WGs of a group on one XCD assuming
// round-robin bid%8 -> XCD). Skips ws round-trip + one launch vs R3.

#define BB   4
#define SS   4096
#define CC   384          // H*D = 6*64
#define BLK  512
#define NBLK 8            // SS/BLK
#define NT   384          // threads per WG (6 waves)
#define NSUB 16           // WGs per block; each writes 32 rows
#define RWS  (BLK / NSUB) // 32
#define CH4  (CC / 4)     // 96 float4 chunks per row

__global__ __launch_bounds__(NT) void dinopool_fused(
    const float* __restrict__ x, float* __restrict__ out) {
  __shared__ float part[4][CC];             // 6 KB
  __shared__ __align__(16) float smean[CC];

  // bid = sub*32 + group ; group = b*NBLK + blk  (XCD-locality swizzle)
  int bid   = blockIdx.x;
  int group = bid & 31;
  int sub   = bid >> 5;
  int blk   = group & (NBLK - 1);
  int b     = group >> 3;
  int t     = threadIdx.x;
  int cq    = t % CH4;                      // float4 chunk within a row
  int g     = t / CH4;                      // row group 0..3

  // ---- full-block column sum (redundant per sub; L2-served) --------------
  const float4* xv = (const float4*)(x + (size_t)(b * SS + blk * BLK) * CC);
  float a0 = 0.f, a1 = 0.f, a2 = 0.f, a3 = 0.f;
#pragma unroll 8
  for (int k = 0; k < BLK / 4; ++k) {       // rows g, g+4, ..., g+508
    float4 v = xv[(size_t)(g + 4 * k) * CH4 + cq];
    a0 += v.x; a1 += v.y; a2 += v.z; a3 += v.w;
  }
  part[g][cq * 4 + 0] = a0;
  part[g][cq * 4 + 1] = a1;
  part[g][cq * 4 + 2] = a2;
  part[g][cq * 4 + 3] = a3;
  __syncthreads();

  float s = 0.f;
#pragma unroll
  for (int gg = 0; gg < 4; ++gg) s += part[gg][t];
  smean[t] = s * (1.0f / (float)BLK);
  __syncthreads();

  // ---- broadcast-write this WG's 32 rows as float4 ------------------------
  const float4* sv = (const float4*)smean;
  float4* ov = (float4*)(out + (size_t)(b * SS + blk * BLK + sub * RWS) * CC);
  const int total = RWS * CH4;              // 3072
  for (int i = t; i < total; i += NT) ov[i] = sv[i % CH4];
}

extern "C" void kernel_launch(void* const* d_in, const int* in_sizes, int n_in,
                              void* d_out, int out_size, void* d_ws,
                              size_t ws_size, hipStream_t stream) {
  const float* x = (const float*)d_in[0];
  float* out = (float*)d_out;
  dinopool_fused<<<BB * NBLK * NSUB, NT, 0, stream>>>(x, out);
}

// Round 6
// 140.050 us; speedup vs baseline: 1.2791x; 1.0926x over previous
//
#include <hip/hip_runtime.h>

// DinoPool: block-diagonal uniform attention == per-512-row-block column mean,
// broadcast to all 512 rows. x, out: [4,4096,384] float32. x1/x2/mask unused.
//
// Scoreboard: R3 two-kernel=143.8us (best) | R5 fused=153.0 (L2 amplification
// 403MB ≈ +9us, matches) | R4 coop=179.1 (coop dispatch + straggler drain).
// R6 = R3 structure, kernel A vectorized to float4 (64 scalar -> 16 vec4
// loads/thread, LDS cross-group reduce). Kernel B unchanged.
// Floor arithmetic: 25.2MB read + 25.2MB write + 1.6MB ws @6.6TB/s ≈ 8.5us
// + 2 graph dispatches. Harness re-poison (256MiB ws fill = 40.5us @83% peak
// + input restores) dominates dur_us and is not controllable.

#define BB   4
#define SS   4096
#define CC   384          // H*D = 6*64
#define BLK  512
#define NBLK 8            // SS/BLK
#define NT   384          // threads per WG (6 waves)
#define RCH  8            // ws partials per block (kernel A WGs per block)
#define ROWS (BLK / RCH)  // 64 rows per kernel-A WG
#define NSUB 16           // kernel-B WGs per block
#define RWS  (BLK / NSUB) // 32 rows per kernel-B WG
#define CH4  (CC / 4)     // 96 float4 chunks per row

// ---------------------------------------------------------------------------
// Kernel A: 64-row partial column sums, float4 loads.
// grid = BB*NBLK*RCH = 256, block = 384 (4 row-groups x 96 float4-chunks).
// ---------------------------------------------------------------------------
__global__ __launch_bounds__(NT) void colsum_f32(
    const float* __restrict__ x, float* __restrict__ ws) {
  __shared__ float part[4][CC];             // 6 KB

  int bid = blockIdx.x;                     // (b*NBLK + blk)*RCH + r
  int r   = bid & (RCH - 1);
  int blk = (bid >> 3) & (NBLK - 1);
  int b   = bid >> 6;
  int t   = threadIdx.x;
  int cq  = t % CH4;                        // float4 chunk within a row
  int g   = t / CH4;                        // row group 0..3

  const float4* xv =
      (const float4*)(x + (size_t)(b * SS + blk * BLK + r * ROWS) * CC);
  float a0 = 0.f, a1 = 0.f, a2 = 0.f, a3 = 0.f;
#pragma unroll
  for (int k = 0; k < ROWS / 4; ++k) {      // 16 iters: rows g, g+4, ...
    float4 v = xv[(size_t)(g + 4 * k) * CH4 + cq];
    a0 += v.x; a1 += v.y; a2 += v.z; a3 += v.w;
  }
  part[g][cq * 4 + 0] = a0;
  part[g][cq * 4 + 1] = a1;
  part[g][cq * 4 + 2] = a2;
  part[g][cq * 4 + 3] = a3;
  __syncthreads();

  float s = 0.f;
#pragma unroll
  for (int gg = 0; gg < 4; ++gg) s += part[gg][t];
  ws[(size_t)bid * CC + t] = s;
}

// ---------------------------------------------------------------------------
// Kernel B: reduce 8 partials -> mean row in LDS; broadcast-write 32 rows.
// grid = BB*NBLK*NSUB = 512, block = 384.  (unchanged from R3)
// ---------------------------------------------------------------------------
__global__ __launch_bounds__(NT) void bcast_f32(
    const float* __restrict__ ws, float* __restrict__ out) {
  __shared__ __align__(16) float smean[CC];

  int bid = blockIdx.x;                     // (b*NBLK + blk)*NSUB + sub
  int sub = bid & (NSUB - 1);
  int blk = (bid >> 4) & (NBLK - 1);
  int b   = bid >> 7;
  int t   = threadIdx.x;

  const float* wp = ws + (size_t)((b * NBLK + blk) * RCH) * CC + t;
  float s = 0.0f;
#pragma unroll
  for (int k = 0; k < RCH; ++k) s += wp[(size_t)k * CC];
  smean[t] = s * (1.0f / (float)BLK);
  __syncthreads();

  const float4* sv = (const float4*)smean;
  float4* ov = (float4*)(out + (size_t)(b * SS + blk * BLK + sub * RWS) * CC);
  const int total = RWS * CH4;              // 3072
  for (int i = t; i < total; i += NT) ov[i] = sv[i % CH4];
}

extern "C" void kernel_launch(void* const* d_in, const int* in_sizes, int n_in,
                              void* d_out, int out_size, void* d_ws,
                              size_t ws_size, hipStream_t stream) {
  const float* x = (const float*)d_in[0];
  float* out = (float*)d_out;
  float* ws = (float*)d_ws;  // 256*384*4 = 393 KB used (ws_size = 256 MiB)

  colsum_f32<<<BB * NBLK * RCH, NT, 0, stream>>>(x, ws);
  bcast_f32<<<BB * NBLK * NSUB, NT, 0, stream>>>(ws, out);
}